// Round 4
// baseline (116.470 us; speedup 1.0000x reference)
//
#include <hip/hip_runtime.h>
#include <math.h>

#define B_ 2
#define N_ 5
#define C_ 256
#define H_ 64
#define W_ 64
#define PARA_ 256
#define H0_ 60
#define W0_ 60
#define LOG2E 1.4426950408889634f

__device__ __forceinline__ float rfl(float x) {
    return __int_as_float(__builtin_amdgcn_readfirstlane(__float_as_int(x)));
}

// ---------------- Kernel 1: fused MLP + heads ----------------
__global__ __launch_bounds__(256) void k_heads(
        const float* __restrict__ pc, const float* __restrict__ W1,
        const float* __restrict__ b1,
        const float* __restrict__ Wk, const float* __restrict__ bk,
        const float* __restrict__ Ws, const float* __restrict__ bs,
        const float* __restrict__ Wr, const float* __restrict__ br,
        float* __restrict__ kpts, float* __restrict__ rad,
        float* __restrict__ sim) {
    int b = blockIdx.x / 35;
    int m = (blockIdx.x % 35) * 256 + threadIdx.x;
    int tid = threadIdx.x;

    __shared__ float spc[PARA_];
    __shared__ float sh[PARA_];
    spc[tid] = pc[b * PARA_ + tid];
    __syncthreads();

    {
        const float4* wrow = (const float4*)(W1 + (size_t)tid * PARA_);
        const float4* sp4 = (const float4*)spc;
        float acc = b1[tid];
        #pragma unroll 8
        for (int k = 0; k < PARA_ / 4; ++k) {
            float4 wv = wrow[k];
            float4 pv = sp4[k];
            acc += wv.x * pv.x + wv.y * pv.y + wv.z * pv.z + wv.w * pv.w;
        }
        sh[tid] = fmaxf(acc, 0.f);
    }
    __syncthreads();

    const float* wrow;
    float bias;
    int kind, j;
    if (m < 2 * N_ * C_) {          // kpts
        j = m; wrow = Wk + (size_t)j * PARA_; bias = bk[j]; kind = 0;
    } else if (m < 3 * N_ * C_) {   // rad
        j = m - 2 * N_ * C_; wrow = Wr + (size_t)j * PARA_; bias = br[j]; kind = 1;
    } else {                        // sim
        j = m - 3 * N_ * C_; wrow = Ws + (size_t)j * PARA_; bias = bs[j]; kind = 2;
    }
    const float4* w4 = (const float4*)wrow;
    const float4* h4 = (const float4*)sh;
    float acc = bias;
    #pragma unroll 8
    for (int k = 0; k < PARA_ / 4; ++k) {
        float4 wv = w4[k];
        float4 hv = h4[k];
        acc += wv.x * hv.x + wv.y * hv.y + wv.z * hv.z + wv.w * hv.w;
    }

    if (kind == 0)      kpts[b * 2 * N_ * C_ + j] = tanhf(acc);
    else if (kind == 1) rad [b * N_ * C_     + j] = 1.f / (1.f + expf(-acc));
    else                sim [b * 4 * N_ * C_ + j] = tanhf(acc);
}

// ---------------- Kernel 2: quarter-split fused warp+resize+sample ----------------
// Block = (b, c, quarter q). Output rows h in [16q, 16q+15].
// Scrambled flat index rfull = w0*120 + h0*2 + t; plane0 = rfull<3600 (w0<30).
// Sample row ih of plane0 needs w0 in [ih/2 .. ih/2(+)], so quarter q needs
// plane0 columns [base0, base0+n0) and plane1 columns [base1, base1+n1):
//   q: rows          base0 n0 base1 n1
//   0: [ 0,15]         0   8   30   8
//   1: [14,30]         7   9   37   9
//   2: [29,45]        14   9   44   9
//   3: [44,59]        22   8   52   8
// sgl layout: local column j (plane0 cols then plane1 cols) * 120 + h0*2 + t.
// Reads: g0 = sgl[ih*60+iw - 120*base0]; g1 = sgl[ih*60+iw + o1adj],
//   o1adj = n0*120 + 3600 - 120*base1.
__global__ __launch_bounds__(256) void k_fused(
        const float* __restrict__ kpts, const float* __restrict__ rad,
        const float* __restrict__ sim,
        const float* __restrict__ fmap, float* __restrict__ out) {
    const int q = blockIdx.x & 3;
    const int c = (blockIdx.x >> 2) & (C_ - 1);
    const int b = blockIdx.x >> 10;
    const int tid = threadIdx.x;

    __shared__ __align__(16) float sgl[2160];   // up to 18 columns x 120
    __shared__ __align__(16) float sf[H_ * W_]; // fmap slice

    const int base0 = (q == 0) ? 0 : (q == 1) ? 7 : (q == 2) ? 14 : 22;
    const int n0    = (q == 0 || q == 3) ? 8 : 9;
    const int base1 = base0 + 30;
    const int ncol  = 2 * n0;
    const int o0    = 120 * base0;
    const int o1adj = n0 * 120 + 3600 - 120 * base1;

    // async stage fmap slice -> sf (drained by the pre-sample __syncthreads)
    {
        const float* fpb = fmap + (((size_t)(b * C_ + c)) << 12);
        int wave = tid >> 6, lane = tid & 63;
        #pragma unroll
        for (int i = 0; i < 4; ++i) {
            const float* src = fpb + wave * 1024 + i * 256 + lane * 4;
            __builtin_amdgcn_global_load_lds(
                (const __attribute__((address_space(1))) void*)src,
                (__attribute__((address_space(3))) void*)(sf + wave * 1024 + i * 256),
                16, 0, 0);
        }
    }

    // block-uniform keypoint params -> SGPRs
    float kx[N_], ky[N_], nlr[N_], s0_[N_], s1h[N_], s2_[N_], s3_[N_];
    #pragma unroll
    for (int n = 0; n < N_; ++n) {
        int base = (b * N_ + n) * C_ + c;
        kx[n]  = rfl(kpts[base * 2 + 0]);
        ky[n]  = rfl(kpts[base * 2 + 1]);
        nlr[n] = rfl(-LOG2E * __builtin_amdgcn_rcpf(rad[base]));
        s0_[n] = rfl(sim[base * 4 + 0]);
        s1h[n] = rfl(sim[base * 4 + 1] * 0.5f);   // revolutions = s1*e/2
        s2_[n] = rfl(sim[base * 4 + 2]);
        s3_[n] = rfl(sim[base * 4 + 3]);
    }

    // warp phase over this block's columns; grid0 is a separable linspace
    const float step = 2.0f / 59.0f;
    const int npx = ncol * 60;
    for (int p = tid; p < npx; p += 256) {
        int j  = p / 60;
        int h0 = p - j * 60;
        int w0 = (j < n0) ? (base0 + j) : (base1 + (j - n0));
        float gx = fmaf((float)w0, step, -1.0f);
        float gy = fmaf((float)h0, step, -1.0f);

        float numx = 0.f, numy = 0.f, den = 0.f;
        #pragma unroll
        for (int n = 0; n < N_; ++n) {
            float ox = gx - kx[n], oy = gy - ky[n];
            float dist = __builtin_amdgcn_sqrtf(fmaf(ox, ox, oy * oy));
            float e = __builtin_amdgcn_exp2f(dist * nlr[n]);
            float scale = fmaf(s0_[n], e, 1.f);
            float ar = s1h[n] * e;
            float sn = __builtin_amdgcn_sinf(ar);
            float cs = __builtin_amdgcn_cosf(ar);
            float rx = fmaf(ox, cs, oy * sn);
            float ry = fmaf(oy, cs, -(ox * sn));
            float wxv = fmaf(scale, rx, fmaf(s2_[n], e, kx[n]));
            float wyv = fmaf(scale, ry, fmaf(s3_[n], e, ky[n]));
            float sw = __builtin_amdgcn_exp2f(e * LOG2E);
            numx = fmaf(wxv, sw, numx);
            numy = fmaf(wyv, sw, numy);
            den += sw;
        }
        float inv = __builtin_amdgcn_rcpf(den);
        *(float2*)(sgl + j * 120 + h0 * 2) = make_float2(numx * inv, numy * inv);
    }
    __syncthreads();   // drains sgl ds_writes AND the sf global_load_lds

    // sample phase: 16 output rows (1024 px), all reads from LDS
    float* outp = out + (((size_t)(b * C_ + c)) << 12);
    const float sc = 60.f / 64.f;
    #pragma unroll
    for (int pp = 0; pp < 4; ++pp) {
        int p = pp * 256 + tid;
        int w = p & (W_ - 1);
        int h = (q << 4) + (p >> 6);

        float chf = ((float)h + 0.5f) * sc - 0.5f;
        float cwf = ((float)w + 0.5f) * sc - 0.5f;
        int ih = (int)floorf(chf), iw = (int)floorf(cwf);
        float th = chf - (float)ih, tw = cwf - (float)iw;
        int ih0 = min(max(ih, 0), H0_ - 1), ih1 = min(max(ih + 1, 0), H0_ - 1);
        int iw0 = min(max(iw, 0), W0_ - 1), iw1 = min(max(iw + 1, 0), W0_ - 1);
        float w00 = (1.f - th) * (1.f - tw), w01 = (1.f - th) * tw;
        float w10 = th * (1.f - tw),         w11 = th * tw;

        int a00 = ih0 * 60 + iw0, a01 = ih0 * 60 + iw1;
        int a10 = ih1 * 60 + iw0, a11 = ih1 * 60 + iw1;
        float g0 = w00 * sgl[a00 - o0] + w01 * sgl[a01 - o0]
                 + w10 * sgl[a10 - o0] + w11 * sgl[a11 - o0];
        float g1 = w00 * sgl[a00 + o1adj] + w01 * sgl[a01 + o1adj]
                 + w10 * sgl[a10 + o1adj] + w11 * sgl[a11 + o1adj];

        // grid_sample bilinear, zeros padding, align_corners=False
        float x = (g0 + 1.f) * ((float)W_ * 0.5f) - 0.5f;
        float y = (g1 + 1.f) * ((float)H_ * 0.5f) - 0.5f;
        int x0 = (int)floorf(x), y0 = (int)floorf(y);
        float tx = x - (float)x0, ty = y - (float)y0;
        float acc = 0.f;
        #pragma unroll
        for (int dy = 0; dy < 2; ++dy) {
            int yi = y0 + dy;
            float wy = dy ? ty : (1.f - ty);
            if (yi < 0 || yi >= H_) continue;
            #pragma unroll
            for (int dx = 0; dx < 2; ++dx) {
                int xi = x0 + dx;
                float wx = dx ? tx : (1.f - tx);
                if (xi < 0 || xi >= W_) continue;
                acc += sf[yi * W_ + xi] * wy * wx;
            }
        }
        outp[(h << 6) | w] = acc;
    }
}

extern "C" void kernel_launch(void* const* d_in, const int* in_sizes, int n_in,
                              void* d_out, int out_size, void* d_ws, size_t ws_size,
                              hipStream_t stream) {
    const float* fmap  = (const float*)d_in[0];
    const float* pc    = (const float*)d_in[1];
    const float* W1    = (const float*)d_in[2];
    const float* b1    = (const float*)d_in[3];
    const float* Wk    = (const float*)d_in[4];
    const float* bk    = (const float*)d_in[5];
    const float* Ws    = (const float*)d_in[6];
    const float* bs    = (const float*)d_in[7];
    const float* Wr    = (const float*)d_in[8];
    const float* br    = (const float*)d_in[9];

    float* ws = (float*)d_ws;
    float* kpts = ws;           // 5120
    float* rad  = ws + 5120;    // 2560
    float* sim  = ws + 7680;    // 10240

    k_heads<<<B_ * 35, 256, 0, stream>>>(pc, W1, b1, Wk, bk, Ws, bs, Wr, br,
                                         kpts, rad, sim);
    k_fused<<<B_ * C_ * 4, 256, 0, stream>>>(kpts, rad, sim, fmap, (float*)d_out);
}

// Round 7
// 113.034 us; speedup vs baseline: 1.0304x; 1.0304x over previous
//
#include <hip/hip_runtime.h>
#include <math.h>

#define B_ 2
#define N_ 5
#define C_ 256
#define H_ 64
#define W_ 64
#define PARA_ 256
#define H0_ 60
#define W0_ 60
#define LOG2E 1.4426950408889634f

__device__ __forceinline__ float rfl(float x) {
    return __int_as_float(__builtin_amdgcn_readfirstlane(__float_as_int(x)));
}

// ---------------- Kernel 1: fused MLP + heads -> packed params ----------------
// param[((b*N + n)*C + c)*8 + slot] = {kx, ky, nlr, s0, s1h, s2, s3, -}
//   nlr = -log2e * (1 + exp(-acc_rad))   (exact 1/sigmoid, no rcp approx)
__global__ __launch_bounds__(256) void k_heads(
        const float* __restrict__ pc, const float* __restrict__ W1,
        const float* __restrict__ b1,
        const float* __restrict__ Wk, const float* __restrict__ bk,
        const float* __restrict__ Ws, const float* __restrict__ bs,
        const float* __restrict__ Wr, const float* __restrict__ br,
        float* __restrict__ param) {
    int b = blockIdx.x / 35;
    int m = (blockIdx.x % 35) * 256 + threadIdx.x;
    int tid = threadIdx.x;

    __shared__ float spc[PARA_];
    __shared__ float sh[PARA_];
    spc[tid] = pc[b * PARA_ + tid];
    __syncthreads();

    {
        const float4* wrow = (const float4*)(W1 + (size_t)tid * PARA_);
        const float4* sp4 = (const float4*)spc;
        float acc = b1[tid];
        #pragma unroll 8
        for (int k = 0; k < PARA_ / 4; ++k) {
            float4 wv = wrow[k];
            float4 pv = sp4[k];
            acc += wv.x * pv.x + wv.y * pv.y + wv.z * pv.z + wv.w * pv.w;
        }
        sh[tid] = fmaxf(acc, 0.f);
    }
    __syncthreads();

    const float* wrow;
    float bias;
    int kind, j;
    if (m < 2 * N_ * C_) {          // kpts
        j = m; wrow = Wk + (size_t)j * PARA_; bias = bk[j]; kind = 0;
    } else if (m < 3 * N_ * C_) {   // rad
        j = m - 2 * N_ * C_; wrow = Wr + (size_t)j * PARA_; bias = br[j]; kind = 1;
    } else {                        // sim
        j = m - 3 * N_ * C_; wrow = Ws + (size_t)j * PARA_; bias = bs[j]; kind = 2;
    }
    const float4* w4 = (const float4*)wrow;
    const float4* h4 = (const float4*)sh;
    float acc = bias;
    #pragma unroll 8
    for (int k = 0; k < PARA_ / 4; ++k) {
        float4 wv = w4[k];
        float4 hv = h4[k];
        acc += wv.x * hv.x + wv.y * hv.y + wv.z * hv.z + wv.w * hv.w;
    }

    if (kind == 0) {                        // j = (n*C+c)*2 + t
        int m2 = j >> 1, t = j & 1;
        param[(b * N_ * C_ + m2) * 8 + t] = tanhf(acc);
    } else if (kind == 1) {                 // j = n*C + c
        param[(b * N_ * C_ + j) * 8 + 2] = -LOG2E * (1.f + expf(-acc));
    } else {                                // j = (n*C+c)*4 + s
        int m4 = j >> 2, s = j & 3;
        float v = tanhf(acc);
        if (s == 1) v *= 0.5f;              // s1h: revolutions = s1*e/2
        param[(b * N_ * C_ + m4) * 8 + 3 + s] = v;
    }
}

// ---------------- Kernel 2: quarter-split fused warp+resize+sample ----------------
// Block = (b, c, quarter q). Output rows h in [16q, 16q+15].
// Scrambled flat index rfull = w0*120 + h0*2 + t; plane0 = w0<30.
//   q: base0 n0   (plane1: base1 = base0+30, same count)
//   0:   0    8
//   1:   7    9
//   2:  14    9
//   3:  22    8
// sgl layout: local col j * 120 + h0*2 + t (plane0 cols then plane1 cols).
__global__ __launch_bounds__(256) void k_fused(
        const float* __restrict__ param,
        const float* __restrict__ fmap, float* __restrict__ out) {
    const int q = blockIdx.x & 3;
    const int c = (blockIdx.x >> 2) & (C_ - 1);
    const int b = blockIdx.x >> 10;
    const int tid = threadIdx.x;

    __shared__ __align__(16) float sgl[2160];   // up to 18 cols x 120
    __shared__ __align__(16) float sf[H_ * W_]; // fmap slice

    const int base0 = (q == 0) ? 0 : (q == 1) ? 7 : (q == 2) ? 14 : 22;
    const int n0    = (q == 0 || q == 3) ? 8 : 9;
    const int base1 = base0 + 30;
    const int ncol  = 2 * n0;
    const int o0    = 120 * base0;
    const int o1adj = n0 * 120 + 3600 - 120 * base1;

    // async stage fmap slice -> sf (drained by the pre-sample __syncthreads)
    {
        const float* fpb = fmap + (((size_t)(b * C_ + c)) << 12);
        int wave = tid >> 6, lane = tid & 63;
        #pragma unroll
        for (int i = 0; i < 4; ++i) {
            const float* src = fpb + wave * 1024 + i * 256 + lane * 4;
            __builtin_amdgcn_global_load_lds(
                (const __attribute__((address_space(1))) void*)src,
                (__attribute__((address_space(3))) void*)(sf + wave * 1024 + i * 256),
                16, 0, 0);
        }
    }

    // packed block-uniform params: 2 x 16B per keypoint
    float kx[N_], ky[N_], nlr[N_], s0_[N_], s1h[N_], s2_[N_], s3_[N_];
    #pragma unroll
    for (int n = 0; n < N_; ++n) {
        const float4* pp = (const float4*)(param + ((size_t)((b * N_ + n) * C_ + c)) * 8);
        float4 pa = pp[0];
        float4 pb = pp[1];
        kx[n]  = rfl(pa.x);  ky[n]  = rfl(pa.y);
        nlr[n] = rfl(pa.z);  s0_[n] = rfl(pa.w);
        s1h[n] = rfl(pb.x);  s2_[n] = rfl(pb.y);  s3_[n] = rfl(pb.z);
    }

    // warp phase; grid0 is a separable linspace
    const float step = 2.0f / 59.0f;
    const int npx = ncol * 60;
    for (int p = tid; p < npx; p += 256) {
        int j  = p / 60;
        int h0 = p - j * 60;
        int w0 = (j < n0) ? (base0 + j) : (base1 + (j - n0));
        float gx = fmaf((float)w0, step, -1.0f);
        float gy = fmaf((float)h0, step, -1.0f);

        float numx = 0.f, numy = 0.f, den = 0.f;
        #pragma unroll
        for (int n = 0; n < N_; ++n) {
            float ox = gx - kx[n], oy = gy - ky[n];
            float dist = __builtin_amdgcn_sqrtf(fmaf(ox, ox, oy * oy));
            float e = __builtin_amdgcn_exp2f(dist * nlr[n]);
            float scale = fmaf(s0_[n], e, 1.f);
            float ar = s1h[n] * e;
            float sn = __builtin_amdgcn_sinf(ar);
            float cs = __builtin_amdgcn_cosf(ar);
            float rx = fmaf(ox, cs, oy * sn);
            float ry = fmaf(oy, cs, -(ox * sn));
            float wxv = fmaf(scale, rx, fmaf(s2_[n], e, kx[n]));
            float wyv = fmaf(scale, ry, fmaf(s3_[n], e, ky[n]));
            float sw = __builtin_amdgcn_exp2f(e * LOG2E);
            numx = fmaf(wxv, sw, numx);
            numy = fmaf(wyv, sw, numy);
            den += sw;
        }
        float inv = __builtin_amdgcn_rcpf(den);
        *(float2*)(sgl + j * 120 + h0 * 2) = make_float2(numx * inv, numy * inv);
    }
    __syncthreads();   // drains sgl ds_writes AND the sf global_load_lds

    // sample phase: 4 adjacent pixels per thread, one float4 store
    const float sc = 60.f / 64.f;
    const int p4 = tid << 2;
    const int w_base = p4 & (W_ - 1);
    const int h = (q << 4) + (p4 >> 6);

    float chf = ((float)h + 0.5f) * sc - 0.5f;
    int ih = (int)floorf(chf);
    float th = chf - (float)ih;
    int ih0 = min(max(ih, 0), H0_ - 1), ih1 = min(max(ih + 1, 0), H0_ - 1);

    float res[4];
    #pragma unroll
    for (int u = 0; u < 4; ++u) {
        int w = w_base + u;
        float cwf = ((float)w + 0.5f) * sc - 0.5f;
        int iw = (int)floorf(cwf);
        float tw = cwf - (float)iw;
        int iw0 = min(max(iw, 0), W0_ - 1), iw1 = min(max(iw + 1, 0), W0_ - 1);
        float w00 = (1.f - th) * (1.f - tw), w01 = (1.f - th) * tw;
        float w10 = th * (1.f - tw),         w11 = th * tw;

        int a00 = ih0 * 60 + iw0, a01 = ih0 * 60 + iw1;
        int a10 = ih1 * 60 + iw0, a11 = ih1 * 60 + iw1;
        float g0 = w00 * sgl[a00 - o0] + w01 * sgl[a01 - o0]
                 + w10 * sgl[a10 - o0] + w11 * sgl[a11 - o0];
        float g1 = w00 * sgl[a00 + o1adj] + w01 * sgl[a01 + o1adj]
                 + w10 * sgl[a10 + o1adj] + w11 * sgl[a11 + o1adj];

        float x = (g0 + 1.f) * ((float)W_ * 0.5f) - 0.5f;
        float y = (g1 + 1.f) * ((float)H_ * 0.5f) - 0.5f;
        int x0 = (int)floorf(x), y0 = (int)floorf(y);
        float tx = x - (float)x0, ty = y - (float)y0;
        float acc = 0.f;
        #pragma unroll
        for (int dy = 0; dy < 2; ++dy) {
            int yi = y0 + dy;
            float wy = dy ? ty : (1.f - ty);
            if (yi < 0 || yi >= H_) continue;
            #pragma unroll
            for (int dx = 0; dx < 2; ++dx) {
                int xi = x0 + dx;
                float wx = dx ? tx : (1.f - tx);
                if (xi < 0 || xi >= W_) continue;
                acc += sf[yi * W_ + xi] * wy * wx;
            }
        }
        res[u] = acc;
    }

    float* outp = out + (((size_t)(b * C_ + c)) << 12);
    *(float4*)(outp + (h << 6) + w_base) = make_float4(res[0], res[1], res[2], res[3]);
}

extern "C" void kernel_launch(void* const* d_in, const int* in_sizes, int n_in,
                              void* d_out, int out_size, void* d_ws, size_t ws_size,
                              hipStream_t stream) {
    const float* fmap = (const float*)d_in[0];
    const float* pc   = (const float*)d_in[1];
    const float* W1   = (const float*)d_in[2];
    const float* b1   = (const float*)d_in[3];
    const float* Wk   = (const float*)d_in[4];
    const float* bk   = (const float*)d_in[5];
    const float* Ws   = (const float*)d_in[6];
    const float* bs   = (const float*)d_in[7];
    const float* Wr   = (const float*)d_in[8];
    const float* br   = (const float*)d_in[9];

    float* param = (float*)d_ws;   // 2*5*256*8 = 20480 floats

    k_heads<<<B_ * 35, 256, 0, stream>>>(pc, W1, b1, Wk, bk, Ws, bs, Wr, br, param);
    k_fused<<<B_ * C_ * 4, 256, 0, stream>>>(param, fmap, (float*)d_out);
}